// Round 1
// 266.794 us; speedup vs baseline: 1.0083x; 1.0083x over previous
//
#include <hip/hip_runtime.h>
#include <stdint.h>

typedef unsigned short u16;
typedef __attribute__((ext_vector_type(8))) __bf16 bf8v;    // A/B fragment: 8 bf16
typedef __attribute__((ext_vector_type(4))) float f4v;      // 16x16 C/D
typedef __attribute__((ext_vector_type(16))) float f16v;    // 32x32 C/D

#define BB 2
#define SS 2048
#define HH 1024

// workspace layout (bytes) — extent 56688640.
// K1..K3 regions are now UNUSED (single-pass attn reuses scale-0 scores).
#define OFF_Q   0u          // Q bf16 [4096][1024]; later attn output (same region)
#define OFF_K0  8388608u
#define OFF_K1  16777216u
#define OFF_K2  20971520u
#define OFF_K3  23068672u
#define OFF_V0  24117248u
#define OFF_V1  32505856u
#define OFF_V2  36700160u
#define OFF_V3  38797312u
#define OFF_WQT 39845888u   // Wqkv^T bf16 [3072][1024]  (6 MB)
#define OFF_WOT 46137344u   // Wout^T bf16 [1024][1024]  (2 MB)
#define OFF_XB  48234496u   // x bf16 [4096][1024]       (8 MB)
#define OFF_SCW 56623104u   // scale weights f32 [4096][4] (64 KB)

__device__ __forceinline__ u16 f2bf(float f) {
    union { float f; uint32_t u; } v; v.f = f;
    uint32_t r = v.u + 0x7fffu + ((v.u >> 16) & 1u);   // RNE
    return (u16)(r >> 16);
}
__device__ __forceinline__ uint32_t pk2(float a, float b) {
    return (uint32_t)f2bf(a) | ((uint32_t)f2bf(b) << 16);
}
// truncation pack (2 VALU): low half <- bf-trunc(a), high half <- bf-trunc(b)
__device__ __forceinline__ uint32_t pkt2(float a, float b) {
    union { float f; uint32_t u; } x, y; x.f = a; y.f = b;
    return (x.u >> 16) | (y.u & 0xffff0000u);
}
__device__ __forceinline__ u16 f2bft(float f) {
    union { float f; uint32_t u; } v; v.f = f;
    return (u16)(v.u >> 16);
}

// ---------------- x f32 -> bf16 ----------------
__global__ __launch_bounds__(256) void xconv_kernel(const float* __restrict__ x,
                                                    u16* __restrict__ xb) {
    size_t t = (size_t)blockIdx.x * 256 + threadIdx.x;
    float4 v = *(const float4*)&x[t * 4];
    uint2 pk; pk.x = pk2(v.x, v.y); pk.y = pk2(v.z, v.w);
    *(uint2*)&xb[t * 4] = pk;
}

// ---------------- W f32 [K][N] -> bf16 W^T [N][K] ----------------
__global__ __launch_bounds__(256) void wconv_kernel(const float* __restrict__ W,
                                                    u16* __restrict__ Wt,
                                                    int N, int K) {
    __shared__ float tile[64][69];
    const int tid = threadIdx.x;
    const int n0 = blockIdx.x * 64, k0 = blockIdx.y * 64;
    const int r = tid >> 4, c4 = (tid & 15) * 4;
#pragma unroll
    for (int it = 0; it < 4; it++) {
        float4 v = *(const float4*)&W[(size_t)(k0 + it * 16 + r) * N + n0 + c4];
        tile[it * 16 + r][c4 + 0] = v.x; tile[it * 16 + r][c4 + 1] = v.y;
        tile[it * 16 + r][c4 + 2] = v.z; tile[it * 16 + r][c4 + 3] = v.w;
    }
    __syncthreads();
#pragma unroll
    for (int it = 0; it < 4; it++) {
        int n = it * 16 + r;
        uint2 pk;
        pk.x = pk2(tile[c4 + 0][n], tile[c4 + 1][n]);
        pk.y = pk2(tile[c4 + 2][n], tile[c4 + 3][n]);
        *(uint2*)&Wt[(size_t)(n0 + n) * K + k0 + c4] = pk;
    }
}

// ---------------- scale weights: softmax(x @ Wscale + bscale) ----------------
__global__ __launch_bounds__(256) void scale_kernel(const float* __restrict__ x,
                                                    const float* __restrict__ Wscale,
                                                    const float* __restrict__ bscale,
                                                    float* __restrict__ scw) {
    const int lane = threadIdx.x & 63;
    const int wid  = threadIdx.x >> 6;
    const int row  = blockIdx.x * 4 + wid;
    float a0 = 0.f, a1 = 0.f, a2 = 0.f, a3 = 0.f;
    for (int i = 0; i < 16; i++) {
        int hh = lane + i * 64;
        float xs = x[(size_t)row * HH + hh];
        float4 wv = *(const float4*)&Wscale[hh * 4];
        a0 += xs * wv.x; a1 += xs * wv.y; a2 += xs * wv.z; a3 += xs * wv.w;
    }
    for (int off = 1; off < 64; off <<= 1) {
        a0 += __shfl_xor(a0, off); a1 += __shfl_xor(a1, off);
        a2 += __shfl_xor(a2, off); a3 += __shfl_xor(a3, off);
    }
    if (lane == 0) {
        a0 += bscale[0]; a1 += bscale[1]; a2 += bscale[2]; a3 += bscale[3];
        float mx = fmaxf(fmaxf(a0, a1), fmaxf(a2, a3));
        float e0 = __expf(a0 - mx), e1 = __expf(a1 - mx);
        float e2 = __expf(a2 - mx), e3 = __expf(a3 - mx);
        float inv = 1.f / (e0 + e1 + e2 + e3);
        float4 o = {e0 * inv, e1 * inv, e2 * inv, e3 * inv};
        *(float4*)&scw[(size_t)row * 4] = o;
    }
}

// ---------------- bf16 MFMA GEMM, A bf16, B pre-transposed bf16 ----------------
// MODE 0: C[M,N] f32 = A@B + bias.  MODE 1: QKV scatter epilogue.
// K is scaled by 1/sqrt(64) * log2(e) so attn can use exp2 directly.
template<int MODE>
__global__ __launch_bounds__(256) void gemm_bt(const u16* __restrict__ A,
                                               const u16* __restrict__ Bt,
                                               const float* __restrict__ bias,
                                               void* __restrict__ Cp,
                                               int N, int K) {
    __shared__ __align__(16) u16 At[128 * 40];
    __shared__ __align__(16) u16 Btl[128 * 40];
    const int tid  = threadIdx.x;
    const int lane = tid & 63;
    const int wid  = tid >> 6;
    const int l15  = lane & 15;
    const int quad = lane >> 4;
    const int wm = wid & 1, wn = wid >> 1;
    const int m0 = blockIdx.y * 128;
    const int n0 = blockIdx.x * 128;
    const int srow = tid >> 2;           // 0..63
    const int sc8  = (tid & 3) * 8;      // 0,8,16,24

    f4v acc[4][4];
#pragma unroll
    for (int i = 0; i < 4; i++)
#pragma unroll
        for (int j = 0; j < 4; j++) acc[i][j] = (f4v){0.f, 0.f, 0.f, 0.f};

    uint4 pa0 = *(const uint4*)(A  + (size_t)(m0 + srow) * K + sc8);
    uint4 pa1 = *(const uint4*)(A  + (size_t)(m0 + srow + 64) * K + sc8);
    uint4 pb0 = *(const uint4*)(Bt + (size_t)(n0 + srow) * K + sc8);
    uint4 pb1 = *(const uint4*)(Bt + (size_t)(n0 + srow + 64) * K + sc8);

    for (int kc = 0; kc < K; kc += 32) {
        __syncthreads();
        *(uint4*)&At[srow * 40 + sc8]         = pa0;
        *(uint4*)&At[(srow + 64) * 40 + sc8]  = pa1;
        *(uint4*)&Btl[srow * 40 + sc8]        = pb0;
        *(uint4*)&Btl[(srow + 64) * 40 + sc8] = pb1;
        __syncthreads();
        if (kc + 32 < K) {
            pa0 = *(const uint4*)(A  + (size_t)(m0 + srow) * K + kc + 32 + sc8);
            pa1 = *(const uint4*)(A  + (size_t)(m0 + srow + 64) * K + kc + 32 + sc8);
            pb0 = *(const uint4*)(Bt + (size_t)(n0 + srow) * K + kc + 32 + sc8);
            pb1 = *(const uint4*)(Bt + (size_t)(n0 + srow + 64) * K + kc + 32 + sc8);
        }
        bf8v af[4], bf[4];
#pragma unroll
        for (int t = 0; t < 4; t++) {
            af[t] = *(const bf8v*)&At[(wm * 64 + t * 16 + l15) * 40 + quad * 8];
            bf[t] = *(const bf8v*)&Btl[(wn * 64 + t * 16 + l15) * 40 + quad * 8];
        }
#pragma unroll
        for (int ti = 0; ti < 4; ti++)
#pragma unroll
            for (int tj = 0; tj < 4; tj++)
                acc[ti][tj] = __builtin_amdgcn_mfma_f32_16x16x32_bf16(af[ti], bf[tj], acc[ti][tj], 0, 0, 0);
    }

    if (MODE == 0) {
#pragma unroll
        for (int ti = 0; ti < 4; ti++)
#pragma unroll
            for (int tj = 0; tj < 4; tj++)
#pragma unroll
                for (int r = 0; r < 4; r++) {
                    int m = m0 + wm * 64 + ti * 16 + quad * 4 + r;
                    int n = n0 + wn * 64 + tj * 16 + l15;
                    ((float*)Cp)[(size_t)m * N + n] = acc[ti][tj][r] + bias[n];
                }
    } else {
        char* ws = (char*)Cp;
        u16* Qd = (u16*)ws;
        u16* K0 = (u16*)(ws + OFF_K0);
        u16* V0 = (u16*)(ws + OFF_V0); u16* V1 = (u16*)(ws + OFF_V1);
        u16* V2 = (u16*)(ws + OFF_V2); u16* V3 = (u16*)(ws + OFF_V3);
        const int region = n0 >> 10;
        if (region == 0) {             // ---- Q dense bf16 [tok][h*64+hd]
#pragma unroll
            for (int ti = 0; ti < 4; ti++)
#pragma unroll
                for (int tj = 0; tj < 4; tj++)
#pragma unroll
                    for (int r = 0; r < 4; r++) {
                        int m = m0 + wm * 64 + ti * 16 + quad * 4 + r;
                        int n = n0 + wn * 64 + tj * 16 + l15;
                        Qd[(size_t)m * 1024 + n] = f2bf(acc[ti][tj][r] + bias[n]);
                    }
        } else if (region == 1) {      // ---- K (only full-res copy), scale 0.125*log2(e)
#pragma unroll
            for (int ti = 0; ti < 4; ti++)
#pragma unroll
                for (int tj = 0; tj < 4; tj++) {
                    int n  = n0 + wn * 64 + tj * 16 + l15;
                    int nk = n - 1024;
                    int h = nk >> 6, hd = nk & 63;
#pragma unroll
                    for (int r = 0; r < 4; r++) {
                        int m = m0 + wm * 64 + ti * 16 + quad * 4 + r;
                        int bb = m >> 11, tok = m & 2047;
                        int bh = bb * 16 + h;
                        u16 bv = f2bf((acc[ti][tj][r] + bias[n]) * 0.18033688f);
                        K0[((size_t)bh * 2048 + tok) * 64 + hd] = bv;
                    }
                }
        } else {                       // ---- V^T dilated copies [b,h,hd,tok]
#pragma unroll
            for (int ti = 0; ti < 4; ti++)
#pragma unroll
                for (int tj = 0; tj < 4; tj++) {
                    int n  = n0 + wn * 64 + tj * 16 + l15;
                    int nv = n - 2048;
                    int h = nv >> 6, hd = nv & 63;
                    int tokb = m0 + wm * 64 + ti * 16 + quad * 4;
                    int bb = tokb >> 11, tok = tokb & 2047;
                    int bh = bb * 16 + h;
                    float v0 = acc[ti][tj][0] + bias[n];
                    float v1 = acc[ti][tj][1] + bias[n];
                    float v2 = acc[ti][tj][2] + bias[n];
                    float v3 = acc[ti][tj][3] + bias[n];
                    u16 c0 = f2bf(v0), c1 = f2bf(v1), c2 = f2bf(v2), c3 = f2bf(v3);
                    uint2 pk;
                    pk.x = (uint32_t)c0 | ((uint32_t)c1 << 16);
                    pk.y = (uint32_t)c2 | ((uint32_t)c3 << 16);
                    *(uint2*)&V0[((size_t)bh * 64 + hd) * 2048 + tok] = pk;
                    *(uint32_t*)&V1[((size_t)bh * 64 + hd) * 1024 + (tok >> 1)] =
                        (uint32_t)c0 | ((uint32_t)c2 << 16);
                    V2[((size_t)bh * 64 + hd) * 512 + (tok >> 2)] = c0;
                    if (!(quad & 1)) V3[((size_t)bh * 64 + hd) * 256 + (tok >> 3)] = c0;
                }
        }
    }
}

// ---------------- multi-scale attention, single K-pass, 4 waves x 32q ----------------
// Key insight: dilated-scale scores are a SUBSET of scale-0 scores (same q,k,scale),
// so QK^T + exp are computed ONCE over the 2048 keys. Per 32-key chunk:
//   P0 full (32 keys)           -> 2x 32x32x16 PV per ht       (every chunk)
//   Pe even keys packed (16)    -> 1x 32x32x16 PV per ht       (every chunk)
//   P2 keys%4==0, 2-chunk group -> 1x 32x32x16 PV per ht       (odd chunks)
//   P3 keys%8==0, 4-chunk group -> 1x 32x32x16 PV per ht       (c%4==3)
// Four separate accumulators (128 VGPR), folded with per-scale 1/ls and softmax
// weights at the end. K pre-scaled by log2(e)*0.125 -> bare v_exp_f32 (exp2f).
__global__ __launch_bounds__(256, 2) void attn_kernel(const char* __restrict__ ws) {
    __shared__ __align__(16) u16 smem[30208];
    u16* Kt0  = smem;            // [32 key][72]
    u16* Kt1  = smem + 2304;
    u16* Vt0  = smem + 4608;     // [64 hd][40]
    u16* Vt1  = smem + 7168;
    u16* V1t0 = smem + 9728;     // [64 hd][24] (16 used)
    u16* V1t1 = smem + 11264;
    u16* V2t  = smem + 12800;    // [64 hd][24], single buffer, 2-chunk groups
    u16* V3t  = smem + 14336;    // [64 hd][24], single buffer, 4-chunk groups

    const u16* Qd    = (const u16*)(ws + OFF_Q);
    const float* scw = (const float*)(ws + OFF_SCW);
    u16* attnb       = (u16*)(ws + OFF_Q);          // aliases Q (block reads Q first)

    const int tid  = threadIdx.x;
    const int lane = tid & 63;
    const int wid  = tid >> 6;
    const int l31  = lane & 31;
    const int half = lane >> 5;
    const int b = blockIdx.z, h = blockIdx.y;
    const int q  = blockIdx.x * 128 + wid * 32 + l31;   // this lane's token
    const int bh = b * 16 + h;

    // per-wave P region: P0[32][40] | Pe[32][24] | P2[32][24] | P3[32][24]
    u16* Pw0 = smem + 15872 + wid * 3584;
    u16* Pwe = Pw0 + 1280;
    u16* Pw2 = Pwe + 768;
    u16* Pw3 = Pw2 + 768;

    // cooperative staging coords (256 threads)
    const int skey = tid >> 3;             // 0..31
    const int shd8 = (tid & 7) * 8;
    const int svhd = tid >> 2;             // 0..63
    const int svk8 = (tid & 3) * 8;
    const int vi4  = (tid & 3) * 4;

    // Q B-frags: qf[ks] = Q[q][h*64 + ks*16 + half*8 + j]
    bf8v qf[4];
#pragma unroll
    for (int ks = 0; ks < 4; ks++)
        qf[ks] = *(const bf8v*)(Qd + (size_t)(b * SS + q) * 1024 + h * 64 + ks * 16 + half * 8);

    const u16* Kb  = (const u16*)(ws + OFF_K0) + (size_t)bh * (2048 * 64);
    const u16* Vb0 = (const u16*)(ws + OFF_V0) + (size_t)bh * (64 * 2048);
    const u16* Vb1 = (const u16*)(ws + OFF_V1) + (size_t)bh * (64 * 1024);
    const u16* Vb2 = (const u16*)(ws + OFF_V2) + (size_t)bh * (64 * 512);
    const u16* Vb3 = (const u16*)(ws + OFF_V3) + (size_t)bh * (64 * 256);

    f16v oacc0[2], oacc1[2], oacc2[2], oacc3[2];
#pragma unroll
    for (int ht = 0; ht < 2; ht++)
#pragma unroll
        for (int r = 0; r < 16; r++) {
            oacc0[ht][r] = 0.f; oacc1[ht][r] = 0.f;
            oacc2[ht][r] = 0.f; oacc3[ht][r] = 0.f;
        }
    float ls0 = 0.f, ls1 = 0.f, ls2 = 0.f, ls3 = 0.f;

    // ---- prime: chunk 0 -> buf0; V2/V3 group-0 regs; prefetch chunk 1 -> regs
    uint4 kr  = *(const uint4*)(Kb + (size_t)skey * 64 + shd8);
    uint4 vr  = *(const uint4*)(Vb0 + (size_t)svhd * 2048 + svk8);
    uint2 v1r = *(const uint2*)(Vb1 + (size_t)svhd * 1024 + vi4);
    uint2 v2r = *(const uint2*)(Vb2 + (size_t)svhd * 512 + vi4);
    uint2 v3r = *(const uint2*)(Vb3 + (size_t)svhd * 256 + vi4);
    *(uint4*)&Kt0[skey * 72 + shd8] = kr;
    *(uint4*)&Vt0[svhd * 40 + svk8] = vr;
    *(uint2*)&V1t0[svhd * 24 + vi4] = v1r;
    kr  = *(const uint4*)(Kb + (size_t)(32 + skey) * 64 + shd8);
    vr  = *(const uint4*)(Vb0 + (size_t)svhd * 2048 + 32 + svk8);
    v1r = *(const uint2*)(Vb1 + (size_t)svhd * 1024 + 16 + vi4);
    __syncthreads();

    for (int c = 0; c < 64; c++) {
        u16* Ktc  = (c & 1) ? Kt1 : Kt0;
        u16* Vtc  = (c & 1) ? Vt1 : Vt0;
        u16* V1tc = (c & 1) ? V1t1 : V1t0;
        u16* Ktn  = (c & 1) ? Kt0 : Kt1;
        u16* Vtn  = (c & 1) ? Vt0 : Vt1;
        u16* V1tn = (c & 1) ? V1t0 : V1t1;

        // ---- QK: S^T col=q(l31), rows=key (log2 domain)
        f16v sa;
#pragma unroll
        for (int r = 0; r < 16; r++) sa[r] = 0.f;
#pragma unroll
        for (int ks = 0; ks < 4; ks++) {
            bf8v ka = *(const bf8v*)&Ktc[l31 * 72 + ks * 16 + half * 8];
            sa = __builtin_amdgcn_mfma_f32_32x32x16_bf16(ka, qf[ks], sa, 0, 0, 0);
        }
        // ---- exp2 + P views; reg r=g*4+i -> key g*8+half*4+i
#pragma unroll
        for (int g = 0; g < 4; g++) {
            float e0 = exp2f(sa[g * 4 + 0]);
            float e1 = exp2f(sa[g * 4 + 1]);
            float e2 = exp2f(sa[g * 4 + 2]);
            float e3 = exp2f(sa[g * 4 + 3]);
            ls0 += (e0 + e1) + (e2 + e3);
            ls1 += e0 + e2;                      // key%2==0 <=> i even
            ls2 += e0;                           // key%4==0 <=> i==0
            if (!half) ls3 += e0;                // key%8==0 <=> i==0 && half==0
            uint2 pk;
            pk.x = pkt2(e0, e1);
            pk.y = pkt2(e2, e3);
            *(uint2*)&Pw0[l31 * 40 + g * 8 + half * 4] = pk;
            *(uint32_t*)&Pwe[l31 * 24 + g * 4 + half * 2] = pkt2(e0, e2);
            Pw2[l31 * 24 + (c & 1) * 8 + g * 2 + half] = f2bft(e0);
            if (!half) Pw3[l31 * 24 + (c & 3) * 4 + g] = f2bft(e0);
        }
        // ---- stage chunk c+1 into the other buffer; V2/V3 group staging
        if (c + 1 < 64) {
            *(uint4*)&Ktn[skey * 72 + shd8] = kr;
            *(uint4*)&Vtn[svhd * 40 + svk8] = vr;
            *(uint2*)&V1tn[svhd * 24 + vi4] = v1r;
        }
        if (!(c & 1)) {                          // group (c,c+1), consumed end of c+1
            *(uint2*)&V2t[svhd * 24 + vi4] = v2r;
            if (!(c & 3))                        // group (c..c+3), consumed end of c+3
                *(uint2*)&V3t[svhd * 24 + vi4] = v3r;
        }
        // ---- prefetch chunk c+2 (and its groups) into regs
        if (c + 2 < 64) {
            kr  = *(const uint4*)(Kb + (size_t)((c + 2) * 32 + skey) * 64 + shd8);
            vr  = *(const uint4*)(Vb0 + (size_t)svhd * 2048 + (c + 2) * 32 + svk8);
            v1r = *(const uint2*)(Vb1 + (size_t)svhd * 1024 + (c + 2) * 16 + vi4);
            if (!((c + 2) & 1))
                v2r = *(const uint2*)(Vb2 + (size_t)svhd * 512 + (c + 2) * 8 + vi4);
            if (!((c + 2) & 3))
                v3r = *(const uint2*)(Vb3 + (size_t)svhd * 256 + (c + 2) * 4 + vi4);
        }
        __asm__ volatile("s_waitcnt lgkmcnt(0)" ::: "memory");
        // ---- PV scale 0: full 32 keys
#pragma unroll
        for (int kst = 0; kst < 2; kst++) {
            bf8v pb = *(const bf8v*)&Pw0[l31 * 40 + kst * 16 + half * 8];
#pragma unroll
            for (int ht = 0; ht < 2; ht++) {
                bf8v va = *(const bf8v*)&Vtc[(ht * 32 + l31) * 40 + kst * 16 + half * 8];
                oacc0[ht] = __builtin_amdgcn_mfma_f32_32x32x16_bf16(va, pb, oacc0[ht], 0, 0, 0);
            }
        }
        // ---- PV scale 1: 16 even keys
        {
            bf8v pb1 = *(const bf8v*)&Pwe[l31 * 24 + half * 8];
#pragma unroll
            for (int ht = 0; ht < 2; ht++) {
                bf8v va1 = *(const bf8v*)&V1tc[(ht * 32 + l31) * 24 + half * 8];
                oacc1[ht] = __builtin_amdgcn_mfma_f32_32x32x16_bf16(va1, pb1, oacc1[ht], 0, 0, 0);
            }
        }
        // ---- PV scale 2: 16 keys per 2-chunk group
        if (c & 1) {
            bf8v pb2 = *(const bf8v*)&Pw2[l31 * 24 + half * 8];
#pragma unroll
            for (int ht = 0; ht < 2; ht++) {
                bf8v va2 = *(const bf8v*)&V2t[(ht * 32 + l31) * 24 + half * 8];
                oacc2[ht] = __builtin_amdgcn_mfma_f32_32x32x16_bf16(va2, pb2, oacc2[ht], 0, 0, 0);
            }
        }
        // ---- PV scale 3: 16 keys per 4-chunk group
        if ((c & 3) == 3) {
            bf8v pb3 = *(const bf8v*)&Pw3[l31 * 24 + half * 8];
#pragma unroll
            for (int ht = 0; ht < 2; ht++) {
                bf8v va3 = *(const bf8v*)&V3t[(ht * 32 + l31) * 24 + half * 8];
                oacc3[ht] = __builtin_amdgcn_mfma_f32_32x32x16_bf16(va3, pb3, oacc3[ht], 0, 0, 0);
            }
        }
        __syncthreads();
    }
    // ---- fold the 4 scales: ofin = sum_s (w_s / ls_s) * oacc_s
    ls0 += __shfl_xor(ls0, 32);
    ls1 += __shfl_xor(ls1, 32);
    ls2 += __shfl_xor(ls2, 32);
    ls3 += __shfl_xor(ls3, 32);
    float4 sw = *(const float4*)&scw[(size_t)(b * SS + q) * 4];
    float w0 = sw.x / ls0, w1 = sw.y / ls1, w2 = sw.z / ls2, w3 = sw.w / ls3;

    const size_t base = (size_t)(b * SS + q) * 1024 + h * 64;
#pragma unroll
    for (int ht = 0; ht < 2; ht++)
#pragma unroll
        for (int g = 0; g < 4; g++) {
            float f0 = w0 * oacc0[ht][g * 4 + 0] + w1 * oacc1[ht][g * 4 + 0]
                     + w2 * oacc2[ht][g * 4 + 0] + w3 * oacc3[ht][g * 4 + 0];
            float f1 = w0 * oacc0[ht][g * 4 + 1] + w1 * oacc1[ht][g * 4 + 1]
                     + w2 * oacc2[ht][g * 4 + 1] + w3 * oacc3[ht][g * 4 + 1];
            float f2 = w0 * oacc0[ht][g * 4 + 2] + w1 * oacc1[ht][g * 4 + 2]
                     + w2 * oacc2[ht][g * 4 + 2] + w3 * oacc3[ht][g * 4 + 2];
            float f3 = w0 * oacc0[ht][g * 4 + 3] + w1 * oacc1[ht][g * 4 + 3]
                     + w2 * oacc2[ht][g * 4 + 3] + w3 * oacc3[ht][g * 4 + 3];
            uint2 pk;
            pk.x = pk2(f0, f1);
            pk.y = pk2(f2, f3);
            *(uint2*)&attnb[base + ht * 32 + g * 8 + half * 4] = pk;
        }
}

extern "C" void kernel_launch(void* const* d_in, const int* in_sizes, int n_in,
                              void* d_out, int out_size, void* d_ws, size_t ws_size,
                              hipStream_t stream) {
    const float* x      = (const float*)d_in[0];
    const float* Wqkv   = (const float*)d_in[1];
    const float* bqkv   = (const float*)d_in[2];
    const float* Wout   = (const float*)d_in[3];
    const float* bout   = (const float*)d_in[4];
    const float* Wscale = (const float*)d_in[5];
    const float* bscale = (const float*)d_in[6];
    float* out = (float*)d_out;

    char* ws = (char*)d_ws;
    u16*   wqt   = (u16*)(ws + OFF_WQT);
    u16*   wot   = (u16*)(ws + OFF_WOT);
    u16*   xb    = (u16*)(ws + OFF_XB);
    u16*   attnb = (u16*)(ws + OFF_Q);
    float* scw   = (float*)(ws + OFF_SCW);

    xconv_kernel<<<dim3(4096), dim3(256), 0, stream>>>(x, xb);
    wconv_kernel<<<dim3(48, 16), dim3(256), 0, stream>>>(Wqkv, wqt, 3072, 1024);
    wconv_kernel<<<dim3(16, 16), dim3(256), 0, stream>>>(Wout, wot, 1024, 1024);
    scale_kernel<<<dim3(1024), dim3(256), 0, stream>>>(x, Wscale, bscale, scw);
    gemm_bt<1><<<dim3(24, 32), dim3(256), 0, stream>>>(xb, wqt, bqkv, (void*)ws, 3072, 1024);
    attn_kernel<<<dim3(16, 16, 2), dim3(256), 0, stream>>>(ws);
    gemm_bt<0><<<dim3(8, 32), dim3(256), 0, stream>>>(attnb, wot, bout, (void*)out, 1024, 1024);
}

// Round 3
// 264.112 us; speedup vs baseline: 1.0185x; 1.0102x over previous
//
#include <hip/hip_runtime.h>
#include <stdint.h>

typedef unsigned short u16;
typedef __attribute__((ext_vector_type(8))) __bf16 bf8v;    // A/B fragment: 8 bf16
typedef __attribute__((ext_vector_type(4))) float f4v;      // 16x16 C/D
typedef __attribute__((ext_vector_type(16))) float f16v;    // 32x32 C/D
typedef __attribute__((ext_vector_type(4))) uint32_t u32x4;

#define BB 2
#define SS 2048
#define HH 1024

// workspace layout (bytes) — extent 56688640.
#define OFF_Q   0u          // Q bf16 [4096][1024]; later attn output (same region)
#define OFF_K0  8388608u
#define OFF_V0  24117248u
#define OFF_V1  32505856u
#define OFF_V2  36700160u
#define OFF_V3  38797312u
#define OFF_WQT 39845888u   // Wqkv^T bf16 [3072][1024]  (6 MB)
#define OFF_WOT 46137344u   // Wout^T bf16 [1024][1024]  (2 MB)
#define OFF_XB  48234496u   // x bf16 [4096][1024]       (8 MB)
#define OFF_SCW 56623104u   // scale weights f32 [4096][4] (64 KB)

__device__ __forceinline__ u16 f2bf(float f) {
    union { float f; uint32_t u; } v; v.f = f;
    uint32_t r = v.u + 0x7fffu + ((v.u >> 16) & 1u);   // RNE
    return (u16)(r >> 16);
}
__device__ __forceinline__ uint32_t pk2(float a, float b) {
    return (uint32_t)f2bf(a) | ((uint32_t)f2bf(b) << 16);
}
// truncation pack (2 VALU): low half <- bf-trunc(a), high half <- bf-trunc(b)
__device__ __forceinline__ uint32_t pkt2(float a, float b) {
    union { float f; uint32_t u; } x, y; x.f = a; y.f = b;
    return (x.u >> 16) | (y.u & 0xffff0000u);
}

// ---------------- x f32 -> bf16 ----------------
__global__ __launch_bounds__(256) void xconv_kernel(const float* __restrict__ x,
                                                    u16* __restrict__ xb) {
    size_t t = (size_t)blockIdx.x * 256 + threadIdx.x;
    float4 v = *(const float4*)&x[t * 4];
    uint2 pk; pk.x = pk2(v.x, v.y); pk.y = pk2(v.z, v.w);
    *(uint2*)&xb[t * 4] = pk;
}

// ---------------- W f32 [K][N] -> bf16 W^T [N][K] ----------------
__global__ __launch_bounds__(256) void wconv_kernel(const float* __restrict__ W,
                                                    u16* __restrict__ Wt,
                                                    int N, int K) {
    __shared__ float tile[64][69];
    const int tid = threadIdx.x;
    const int n0 = blockIdx.x * 64, k0 = blockIdx.y * 64;
    const int r = tid >> 4, c4 = (tid & 15) * 4;
#pragma unroll
    for (int it = 0; it < 4; it++) {
        float4 v = *(const float4*)&W[(size_t)(k0 + it * 16 + r) * N + n0 + c4];
        tile[it * 16 + r][c4 + 0] = v.x; tile[it * 16 + r][c4 + 1] = v.y;
        tile[it * 16 + r][c4 + 2] = v.z; tile[it * 16 + r][c4 + 3] = v.w;
    }
    __syncthreads();
#pragma unroll
    for (int it = 0; it < 4; it++) {
        int n = it * 16 + r;
        uint2 pk;
        pk.x = pk2(tile[c4 + 0][n], tile[c4 + 1][n]);
        pk.y = pk2(tile[c4 + 2][n], tile[c4 + 3][n]);
        *(uint2*)&Wt[(size_t)(n0 + n) * K + k0 + c4] = pk;
    }
}

// ---------------- scale weights: softmax(x @ Wscale + bscale) ----------------
__global__ __launch_bounds__(256) void scale_kernel(const float* __restrict__ x,
                                                    const float* __restrict__ Wscale,
                                                    const float* __restrict__ bscale,
                                                    float* __restrict__ scw) {
    const int lane = threadIdx.x & 63;
    const int wid  = threadIdx.x >> 6;
    const int row  = blockIdx.x * 4 + wid;
    float a0 = 0.f, a1 = 0.f, a2 = 0.f, a3 = 0.f;
    for (int i = 0; i < 16; i++) {
        int hh = lane + i * 64;
        float xs = x[(size_t)row * HH + hh];
        float4 wv = *(const float4*)&Wscale[hh * 4];
        a0 += xs * wv.x; a1 += xs * wv.y; a2 += xs * wv.z; a3 += xs * wv.w;
    }
    for (int off = 1; off < 64; off <<= 1) {
        a0 += __shfl_xor(a0, off); a1 += __shfl_xor(a1, off);
        a2 += __shfl_xor(a2, off); a3 += __shfl_xor(a3, off);
    }
    if (lane == 0) {
        a0 += bscale[0]; a1 += bscale[1]; a2 += bscale[2]; a3 += bscale[3];
        float mx = fmaxf(fmaxf(a0, a1), fmaxf(a2, a3));
        float e0 = __expf(a0 - mx), e1 = __expf(a1 - mx);
        float e2 = __expf(a2 - mx), e3 = __expf(a3 - mx);
        float inv = 1.f / (e0 + e1 + e2 + e3);
        float4 o = {e0 * inv, e1 * inv, e2 * inv, e3 * inv};
        *(float4*)&scw[(size_t)row * 4] = o;
    }
}

// ---------------- bf16 MFMA GEMM, A bf16, B pre-transposed bf16 ----------------
// MODE 0: C[M,N] f32 = A@B + bias.  MODE 1: QKV scatter epilogue.
// K scaled by 1/sqrt(64) * log2(e) so attn can use exp2 directly.
// V0/V1 are stored KEY-PERMUTED (within 16-blocks) so the attn PV B-fragments
// are lane-local: V0 pos = tok with bits2<->3 swapped; V1 pos = 8h+2g+u for
// kk = 4g+2h+u. (Permuting the MFMA contraction index identically on both
// operands leaves the product unchanged.)
template<int MODE>
__global__ __launch_bounds__(256) void gemm_bt(const u16* __restrict__ A,
                                               const u16* __restrict__ Bt,
                                               const float* __restrict__ bias,
                                               void* __restrict__ Cp,
                                               int N, int K) {
    __shared__ __align__(16) u16 At[128 * 40];
    __shared__ __align__(16) u16 Btl[128 * 40];
    const int tid  = threadIdx.x;
    const int lane = tid & 63;
    const int wid  = tid >> 6;
    const int l15  = lane & 15;
    const int quad = lane >> 4;
    const int wm = wid & 1, wn = wid >> 1;
    const int m0 = blockIdx.y * 128;
    const int n0 = blockIdx.x * 128;
    const int srow = tid >> 2;           // 0..63
    const int sc8  = (tid & 3) * 8;      // 0,8,16,24

    f4v acc[4][4];
#pragma unroll
    for (int i = 0; i < 4; i++)
#pragma unroll
        for (int j = 0; j < 4; j++) acc[i][j] = (f4v){0.f, 0.f, 0.f, 0.f};

    uint4 pa0 = *(const uint4*)(A  + (size_t)(m0 + srow) * K + sc8);
    uint4 pa1 = *(const uint4*)(A  + (size_t)(m0 + srow + 64) * K + sc8);
    uint4 pb0 = *(const uint4*)(Bt + (size_t)(n0 + srow) * K + sc8);
    uint4 pb1 = *(const uint4*)(Bt + (size_t)(n0 + srow + 64) * K + sc8);

    for (int kc = 0; kc < K; kc += 32) {
        __syncthreads();
        *(uint4*)&At[srow * 40 + sc8]         = pa0;
        *(uint4*)&At[(srow + 64) * 40 + sc8]  = pa1;
        *(uint4*)&Btl[srow * 40 + sc8]        = pb0;
        *(uint4*)&Btl[(srow + 64) * 40 + sc8] = pb1;
        __syncthreads();
        if (kc + 32 < K) {
            pa0 = *(const uint4*)(A  + (size_t)(m0 + srow) * K + kc + 32 + sc8);
            pa1 = *(const uint4*)(A  + (size_t)(m0 + srow + 64) * K + kc + 32 + sc8);
            pb0 = *(const uint4*)(Bt + (size_t)(n0 + srow) * K + kc + 32 + sc8);
            pb1 = *(const uint4*)(Bt + (size_t)(n0 + srow + 64) * K + kc + 32 + sc8);
        }
        bf8v af[4], bf[4];
#pragma unroll
        for (int t = 0; t < 4; t++) {
            af[t] = *(const bf8v*)&At[(wm * 64 + t * 16 + l15) * 40 + quad * 8];
            bf[t] = *(const bf8v*)&Btl[(wn * 64 + t * 16 + l15) * 40 + quad * 8];
        }
#pragma unroll
        for (int ti = 0; ti < 4; ti++)
#pragma unroll
            for (int tj = 0; tj < 4; tj++)
                acc[ti][tj] = __builtin_amdgcn_mfma_f32_16x16x32_bf16(af[ti], bf[tj], acc[ti][tj], 0, 0, 0);
    }

    if (MODE == 0) {
#pragma unroll
        for (int ti = 0; ti < 4; ti++)
#pragma unroll
            for (int tj = 0; tj < 4; tj++)
#pragma unroll
                for (int r = 0; r < 4; r++) {
                    int m = m0 + wm * 64 + ti * 16 + quad * 4 + r;
                    int n = n0 + wn * 64 + tj * 16 + l15;
                    ((float*)Cp)[(size_t)m * N + n] = acc[ti][tj][r] + bias[n];
                }
    } else {
        char* ws = (char*)Cp;
        u16* Qd = (u16*)ws;
        u16* K0 = (u16*)(ws + OFF_K0);
        u16* V0 = (u16*)(ws + OFF_V0); u16* V1 = (u16*)(ws + OFF_V1);
        u16* V2 = (u16*)(ws + OFF_V2); u16* V3 = (u16*)(ws + OFF_V3);
        const int region = n0 >> 10;
        if (region == 0) {             // ---- Q dense bf16 [tok][h*64+hd]
#pragma unroll
            for (int ti = 0; ti < 4; ti++)
#pragma unroll
                for (int tj = 0; tj < 4; tj++)
#pragma unroll
                    for (int r = 0; r < 4; r++) {
                        int m = m0 + wm * 64 + ti * 16 + quad * 4 + r;
                        int n = n0 + wn * 64 + tj * 16 + l15;
                        Qd[(size_t)m * 1024 + n] = f2bf(acc[ti][tj][r] + bias[n]);
                    }
        } else if (region == 1) {      // ---- K (only full-res copy), scale 0.125*log2(e)
#pragma unroll
            for (int ti = 0; ti < 4; ti++)
#pragma unroll
                for (int tj = 0; tj < 4; tj++) {
                    int n  = n0 + wn * 64 + tj * 16 + l15;
                    int nk = n - 1024;
                    int h = nk >> 6, hd = nk & 63;
#pragma unroll
                    for (int r = 0; r < 4; r++) {
                        int m = m0 + wm * 64 + ti * 16 + quad * 4 + r;
                        int bb = m >> 11, tok = m & 2047;
                        int bh = bb * 16 + h;
                        u16 bv = f2bf((acc[ti][tj][r] + bias[n]) * 0.18033688f);
                        K0[((size_t)bh * 2048 + tok) * 64 + hd] = bv;
                    }
                }
        } else {                       // ---- V^T dilated copies [b,h,hd,tok], permuted
#pragma unroll
            for (int ti = 0; ti < 4; ti++)
#pragma unroll
                for (int tj = 0; tj < 4; tj++) {
                    int n  = n0 + wn * 64 + tj * 16 + l15;
                    int nv = n - 2048;
                    int h = nv >> 6, hd = nv & 63;
                    int tokb = m0 + wm * 64 + ti * 16 + quad * 4;
                    int bb = tokb >> 11, tok = tokb & 2047;
                    int bh = bb * 16 + h;
                    float v0 = acc[ti][tj][0] + bias[n];
                    float v1 = acc[ti][tj][1] + bias[n];
                    float v2 = acc[ti][tj][2] + bias[n];
                    float v3 = acc[ti][tj][3] + bias[n];
                    u16 c0 = f2bf(v0), c1 = f2bf(v1), c2 = f2bf(v2), c3 = f2bf(v3);
                    uint2 pk;
                    pk.x = (uint32_t)c0 | ((uint32_t)c1 << 16);
                    pk.y = (uint32_t)c2 | ((uint32_t)c3 << 16);
                    // V0: swap bits 2<->3 of token index (tok%4==0, run of 4 intact)
                    int tokp = (tok & ~15) | ((tok & 4) << 1) | ((tok & 8) >> 1);
                    *(uint2*)&V0[((size_t)bh * 64 + hd) * 2048 + tokp] = pk;
                    // V1: kk=tok>>1 (even); pos = 8h+2g+u for kk=4g+2h+u
                    int kk = tok >> 1;
                    int v1p = (kk & ~15) | ((kk & 2) << 2) | ((kk & 12) >> 1);
                    *(uint32_t*)&V1[((size_t)bh * 64 + hd) * 1024 + v1p] =
                        (uint32_t)c0 | ((uint32_t)c2 << 16);
                    // V2: pos = 8h+4par+g for t = 8par+2g+h (t=tok>>2)
                    int t2 = tok >> 2;
                    int v2i = (t2 & ~15) | ((t2 & 1) << 3) | ((t2 & 15) >> 1);
                    V2[((size_t)bh * 64 + hd) * 512 + v2i] = c0;
                    // V3: natural order
                    if (!(quad & 1)) V3[((size_t)bh * 64 + hd) * 256 + (tok >> 3)] = c0;
                }
        }
    }
}

// ---------------- multi-scale attention, single K-pass, lane-local P ----------------
// After swapped QK (S^T = K.Q^T, col=q=l31), lane (l31,half) holds e[key 8g+4*half+i].
// V0/V1/V2 are stored key-permuted (see gemm epilogue) so that ALL PV B-fragment
// words are lane-local packs of this lane's own e-values — zero cross-lane ops:
//   scale0 kst: words pkt2(e[kst*8+2w], e[kst*8+2w+1])          (every chunk)
//   scale1:     words pkt2(e[4w], e[4w+2])                      (every chunk)
//   scale2:     {Pa[even], Pb[even], Pa[odd], Pb[odd]}          (odd chunks)
//   scale3:     natural V3 order; half1 words via __shfl_xor(.,32) (c%4==3)
// Chunk loop unrolled x4 so Pa[4]/Pb[4] keep static indices (no scratch).
__global__ __launch_bounds__(256, 2) void attn_kernel(const char* __restrict__ ws) {
    __shared__ __align__(16) u16 smem[15872];
    u16* Kt0  = smem;            // [32 key][72]
    u16* Kt1  = smem + 2304;
    u16* Vt0  = smem + 4608;     // [64 hd][40]
    u16* Vt1  = smem + 7168;
    u16* V1t0 = smem + 9728;     // [64 hd][24] (16 used)
    u16* V1t1 = smem + 11264;
    u16* V2t  = smem + 12800;    // [64 hd][24], single buffer, 2-chunk groups
    u16* V3t  = smem + 14336;    // [64 hd][24], single buffer, 4-chunk groups

    const u16* Qd    = (const u16*)(ws + OFF_Q);
    const float* scw = (const float*)(ws + OFF_SCW);
    u16* attnb       = (u16*)(ws + OFF_Q);          // aliases Q (block reads Q first)

    const int tid  = threadIdx.x;
    const int lane = tid & 63;
    const int wid  = tid >> 6;
    const int l31  = lane & 31;
    const int half = lane >> 5;
    const int b = blockIdx.z, h = blockIdx.y;
    const int q  = blockIdx.x * 128 + wid * 32 + l31;   // this lane's token
    const int bh = b * 16 + h;

    // cooperative staging coords (256 threads)
    const int skey = tid >> 3;             // 0..31
    const int shd8 = (tid & 7) * 8;
    const int svhd = tid >> 2;             // 0..63
    const int svk8 = (tid & 3) * 8;
    const int vi4  = (tid & 3) * 4;

    // Q B-frags: qf[ks] = Q[q][h*64 + ks*16 + half*8 + j]
    bf8v qf[4];
#pragma unroll
    for (int ks = 0; ks < 4; ks++)
        qf[ks] = *(const bf8v*)(Qd + (size_t)(b * SS + q) * 1024 + h * 64 + ks * 16 + half * 8);

    const u16* Kb  = (const u16*)(ws + OFF_K0) + (size_t)bh * (2048 * 64);
    const u16* Vb0 = (const u16*)(ws + OFF_V0) + (size_t)bh * (64 * 2048);
    const u16* Vb1 = (const u16*)(ws + OFF_V1) + (size_t)bh * (64 * 1024);
    const u16* Vb2 = (const u16*)(ws + OFF_V2) + (size_t)bh * (64 * 512);
    const u16* Vb3 = (const u16*)(ws + OFF_V3) + (size_t)bh * (64 * 256);

    f16v oacc0[2], oacc1[2], oacc2[2], oacc3[2];
#pragma unroll
    for (int ht = 0; ht < 2; ht++)
#pragma unroll
        for (int r = 0; r < 16; r++) {
            oacc0[ht][r] = 0.f; oacc1[ht][r] = 0.f;
            oacc2[ht][r] = 0.f; oacc3[ht][r] = 0.f;
        }
    float ls0 = 0.f, ls1 = 0.f, ls2 = 0.f, ls3 = 0.f;

    // ---- prime: chunk 0 -> buf0; V2/V3 group-0 regs; prefetch chunk 1 -> regs
    uint4 kr  = *(const uint4*)(Kb + (size_t)skey * 64 + shd8);
    uint4 vr  = *(const uint4*)(Vb0 + (size_t)svhd * 2048 + svk8);
    uint2 v1r = *(const uint2*)(Vb1 + (size_t)svhd * 1024 + vi4);
    uint2 v2r = *(const uint2*)(Vb2 + (size_t)svhd * 512 + vi4);
    uint2 v3r = *(const uint2*)(Vb3 + (size_t)svhd * 256 + vi4);
    *(uint4*)&Kt0[skey * 72 + shd8] = kr;
    *(uint4*)&Vt0[svhd * 40 + svk8] = vr;
    *(uint2*)&V1t0[svhd * 24 + vi4] = v1r;
    kr  = *(const uint4*)(Kb + (size_t)(32 + skey) * 64 + shd8);
    vr  = *(const uint4*)(Vb0 + (size_t)svhd * 2048 + 32 + svk8);
    v1r = *(const uint2*)(Vb1 + (size_t)svhd * 1024 + 16 + vi4);
    __syncthreads();

    uint32_t Pa[4], Pb[4];
    union uu { u32x4 u; bf8v b; };

    for (int cc = 0; cc < 64; cc += 4) {
#pragma unroll
        for (int ph = 0; ph < 4; ph++) {
            const int c = cc + ph;
            u16* Ktc  = (ph & 1) ? Kt1 : Kt0;
            u16* Vtc  = (ph & 1) ? Vt1 : Vt0;
            u16* V1tc = (ph & 1) ? V1t1 : V1t0;
            u16* Ktn  = (ph & 1) ? Kt0 : Kt1;
            u16* Vtn  = (ph & 1) ? Vt0 : Vt1;
            u16* V1tn = (ph & 1) ? V1t0 : V1t1;

            // ---- QK: S^T col=q(l31), rows=key (log2 domain)
            f16v sa;
#pragma unroll
            for (int r = 0; r < 16; r++) sa[r] = 0.f;
#pragma unroll
            for (int ks = 0; ks < 4; ks++) {
                bf8v ka = *(const bf8v*)&Ktc[l31 * 72 + ks * 16 + half * 8];
                sa = __builtin_amdgcn_mfma_f32_32x32x16_bf16(ka, qf[ks], sa, 0, 0, 0);
            }
            // ---- exp2; e[g*4+i] = e[key 8g + 4*half + i]
            float e[16];
#pragma unroll
            for (int g = 0; g < 4; g++) {
                float e0 = exp2f(sa[g * 4 + 0]);
                float e1 = exp2f(sa[g * 4 + 1]);
                float e2 = exp2f(sa[g * 4 + 2]);
                float e3 = exp2f(sa[g * 4 + 3]);
                e[g * 4 + 0] = e0; e[g * 4 + 1] = e1;
                e[g * 4 + 2] = e2; e[g * 4 + 3] = e3;
                ls0 += (e0 + e1) + (e2 + e3);
                ls1 += e0 + e2;
                ls2 += e0;
                if (!half) ls3 += e0;
            }
            // ---- lane-local fragment packs (truncation-bf16)
            uint32_t F00 = pkt2(e[0],  e[1]),  F01 = pkt2(e[2],  e[3]);
            uint32_t F02 = pkt2(e[4],  e[5]),  F03 = pkt2(e[6],  e[7]);
            uint32_t F10 = pkt2(e[8],  e[9]),  F11 = pkt2(e[10], e[11]);
            uint32_t F12 = pkt2(e[12], e[13]), F13 = pkt2(e[14], e[15]);
            uint32_t G0 = pkt2(e[0],  e[2]),   G1 = pkt2(e[4],  e[6]);
            uint32_t G2 = pkt2(e[8],  e[10]),  G3 = pkt2(e[12], e[14]);
            Pa[ph] = pkt2(e[0], e[4]);   // (g0,g1) i=0 — scale2/3
            Pb[ph] = pkt2(e[8], e[12]);  // (g2,g3) i=0

            // ---- stage chunk c+1 into the other buffer; V2/V3 group staging
            if (c + 1 < 64) {
                *(uint4*)&Ktn[skey * 72 + shd8] = kr;
                *(uint4*)&Vtn[svhd * 40 + svk8] = vr;
                *(uint2*)&V1tn[svhd * 24 + vi4] = v1r;
            }
            if (!(ph & 1)) {                     // group (c,c+1), consumed end of c+1
                *(uint2*)&V2t[svhd * 24 + vi4] = v2r;
                if (ph == 0)                     // group (c..c+3), consumed end of c+3
                    *(uint2*)&V3t[svhd * 24 + vi4] = v3r;
            }
            // ---- prefetch chunk c+2 (and its groups) into regs
            if (c + 2 < 64) {
                kr  = *(const uint4*)(Kb + (size_t)((c + 2) * 32 + skey) * 64 + shd8);
                vr  = *(const uint4*)(Vb0 + (size_t)svhd * 2048 + (c + 2) * 32 + svk8);
                v1r = *(const uint2*)(Vb1 + (size_t)svhd * 1024 + (c + 2) * 16 + vi4);
                if (!((c + 2) & 1))
                    v2r = *(const uint2*)(Vb2 + (size_t)svhd * 512 + (c + 2) * 8 + vi4);
                if (!((c + 2) & 3))
                    v3r = *(const uint2*)(Vb3 + (size_t)svhd * 256 + (c + 2) * 4 + vi4);
            }
            // ---- PV scale 0: full 32 keys (permuted V0 order)
            {
                uu p0; p0.u = (u32x4){F00, F01, F02, F03};
#pragma unroll
                for (int ht = 0; ht < 2; ht++) {
                    bf8v va = *(const bf8v*)&Vtc[(ht * 32 + l31) * 40 + half * 8];
                    oacc0[ht] = __builtin_amdgcn_mfma_f32_32x32x16_bf16(va, p0.b, oacc0[ht], 0, 0, 0);
                }
                uu p1; p1.u = (u32x4){F10, F11, F12, F13};
#pragma unroll
                for (int ht = 0; ht < 2; ht++) {
                    bf8v va = *(const bf8v*)&Vtc[(ht * 32 + l31) * 40 + 16 + half * 8];
                    oacc0[ht] = __builtin_amdgcn_mfma_f32_32x32x16_bf16(va, p1.b, oacc0[ht], 0, 0, 0);
                }
            }
            // ---- PV scale 1: 16 even keys (permuted V1 order)
            {
                uu ps; ps.u = (u32x4){G0, G1, G2, G3};
#pragma unroll
                for (int ht = 0; ht < 2; ht++) {
                    bf8v va1 = *(const bf8v*)&V1tc[(ht * 32 + l31) * 24 + half * 8];
                    oacc1[ht] = __builtin_amdgcn_mfma_f32_32x32x16_bf16(va1, ps.b, oacc1[ht], 0, 0, 0);
                }
            }
            // ---- PV scale 2: 16 keys per 2-chunk group (lane-local, V2 permuted)
            if (ph == 1 || ph == 3) {
                uu p2; p2.u = (u32x4){Pa[ph - 1], Pb[ph - 1], Pa[ph], Pb[ph]};
#pragma unroll
                for (int ht = 0; ht < 2; ht++) {
                    bf8v va2 = *(const bf8v*)&V2t[(ht * 32 + l31) * 24 + half * 8];
                    oacc2[ht] = __builtin_amdgcn_mfma_f32_32x32x16_bf16(va2, p2.b, oacc2[ht], 0, 0, 0);
                }
            }
            // ---- PV scale 3: 16 keys per 4-chunk group (V3 natural; half1 via shfl)
            if (ph == 3) {
                uint32_t t0 = __shfl_xor(Pa[2], 32);
                uint32_t t1 = __shfl_xor(Pb[2], 32);
                uint32_t t2 = __shfl_xor(Pa[3], 32);
                uint32_t t3 = __shfl_xor(Pb[3], 32);
                uint32_t w0 = half ? t0 : Pa[0];
                uint32_t w1 = half ? t1 : Pb[0];
                uint32_t w2 = half ? t2 : Pa[1];
                uint32_t w3 = half ? t3 : Pb[1];
                uu p3; p3.u = (u32x4){w0, w1, w2, w3};
#pragma unroll
                for (int ht = 0; ht < 2; ht++) {
                    bf8v va3 = *(const bf8v*)&V3t[(ht * 32 + l31) * 24 + half * 8];
                    oacc3[ht] = __builtin_amdgcn_mfma_f32_32x32x16_bf16(va3, p3.b, oacc3[ht], 0, 0, 0);
                }
            }
            __syncthreads();
        }
    }
    // ---- fold the 4 scales: ofin = sum_s (w_s / ls_s) * oacc_s
    ls0 += __shfl_xor(ls0, 32);
    ls1 += __shfl_xor(ls1, 32);
    ls2 += __shfl_xor(ls2, 32);
    ls3 += __shfl_xor(ls3, 32);
    float4 sw = *(const float4*)&scw[(size_t)(b * SS + q) * 4];
    float w0 = sw.x / ls0, w1 = sw.y / ls1, w2 = sw.z / ls2, w3 = sw.w / ls3;

    const size_t base = (size_t)(b * SS + q) * 1024 + h * 64;
#pragma unroll
    for (int ht = 0; ht < 2; ht++)
#pragma unroll
        for (int g = 0; g < 4; g++) {
            float f0 = w0 * oacc0[ht][g * 4 + 0] + w1 * oacc1[ht][g * 4 + 0]
                     + w2 * oacc2[ht][g * 4 + 0] + w3 * oacc3[ht][g * 4 + 0];
            float f1 = w0 * oacc0[ht][g * 4 + 1] + w1 * oacc1[ht][g * 4 + 1]
                     + w2 * oacc2[ht][g * 4 + 1] + w3 * oacc3[ht][g * 4 + 1];
            float f2 = w0 * oacc0[ht][g * 4 + 2] + w1 * oacc1[ht][g * 4 + 2]
                     + w2 * oacc2[ht][g * 4 + 2] + w3 * oacc3[ht][g * 4 + 2];
            float f3 = w0 * oacc0[ht][g * 4 + 3] + w1 * oacc1[ht][g * 4 + 3]
                     + w2 * oacc2[ht][g * 4 + 3] + w3 * oacc3[ht][g * 4 + 3];
            uint2 pk;
            pk.x = pk2(f0, f1);
            pk.y = pk2(f2, f3);
            *(uint2*)&attnb[base + ht * 32 + g * 8 + half * 4] = pk;
        }
}

extern "C" void kernel_launch(void* const* d_in, const int* in_sizes, int n_in,
                              void* d_out, int out_size, void* d_ws, size_t ws_size,
                              hipStream_t stream) {
    const float* x      = (const float*)d_in[0];
    const float* Wqkv   = (const float*)d_in[1];
    const float* bqkv   = (const float*)d_in[2];
    const float* Wout   = (const float*)d_in[3];
    const float* bout   = (const float*)d_in[4];
    const float* Wscale = (const float*)d_in[5];
    const float* bscale = (const float*)d_in[6];
    float* out = (float*)d_out;

    char* ws = (char*)d_ws;
    u16*   wqt   = (u16*)(ws + OFF_WQT);
    u16*   wot   = (u16*)(ws + OFF_WOT);
    u16*   xb    = (u16*)(ws + OFF_XB);
    u16*   attnb = (u16*)(ws + OFF_Q);
    float* scw   = (float*)(ws + OFF_SCW);

    xconv_kernel<<<dim3(4096), dim3(256), 0, stream>>>(x, xb);
    wconv_kernel<<<dim3(48, 16), dim3(256), 0, stream>>>(Wqkv, wqt, 3072, 1024);
    wconv_kernel<<<dim3(16, 16), dim3(256), 0, stream>>>(Wout, wot, 1024, 1024);
    scale_kernel<<<dim3(1024), dim3(256), 0, stream>>>(x, Wscale, bscale, scw);
    gemm_bt<1><<<dim3(24, 32), dim3(256), 0, stream>>>(xb, wqt, bqkv, (void*)ws, 3072, 1024);
    attn_kernel<<<dim3(16, 16, 2), dim3(256), 0, stream>>>(ws);
    gemm_bt<0><<<dim3(8, 32), dim3(256), 0, stream>>>(attnb, wot, bout, (void*)out, 1024, 1024);
}